// Round 1
// baseline (680.826 us; speedup 1.0000x reference)
//
#include <hip/hip_runtime.h>
#include <stdint.h>

typedef float   f32x4  __attribute__((ext_vector_type(4)));
typedef __bf16  bf16x8 __attribute__((ext_vector_type(8)));
typedef __bf16  bf16x4 __attribute__((ext_vector_type(4)));
typedef uint32_t u32x4 __attribute__((ext_vector_type(4)));

#define NN 8192
#define MID 128
#define EMB 64

// ---------------- zero rsum ----------------
__global__ void k_zero(float* __restrict__ p, int n) {
  int i = blockIdx.x * 256 + threadIdx.x;
  if (i < n) p[i] = 0.f;
}

// ---------------- XW1^T = (X @ W1)^T, bf16 [128][8192] ----------------
__global__ __launch_bounds__(256) void k_xw1(const float* __restrict__ X,
    const float* __restrict__ W1, __bf16* __restrict__ XW1t) {
  const int t = threadIdx.x;
  const int j = t & 127, r2 = t >> 7;
  const long row = (long)blockIdx.x * 2 + r2;   // wave-uniform row
  const f32x4* xr = (const f32x4*)(X + row * 256);
  float acc = 0.f;
#pragma unroll 8
  for (int k4 = 0; k4 < 64; ++k4) {
    f32x4 xv = xr[k4];
#pragma unroll
    for (int u = 0; u < 4; ++u)
      acc += xv[u] * W1[(k4 * 4 + u) * 128 + j];
  }
  XW1t[(long)j * NN + row] = (__bf16)acc;
}

// ---------------- reduce split-K partials -> relu -> bf16 h ----------------
__global__ __launch_bounds__(256) void k_reduce1(const float* __restrict__ hpart,
    __bf16* __restrict__ hbf) {
  const long idx = (long)blockIdx.x * 256 + threadIdx.x;  // < 8192*128
  float v = hpart[idx] + hpart[idx + 1048576] + hpart[idx + 2097152] + hpart[idx + 3145728];
  v = fmaxf(v, 0.f);
  hbf[idx] = (__bf16)v;
}

// ---------------- Y^T = (h @ W2)^T, bf16 [64][8192] ----------------
__global__ __launch_bounds__(256) void k_yt(const __bf16* __restrict__ hbf,
    const float* __restrict__ W2, __bf16* __restrict__ Yt) {
  const int t = threadIdx.x;
  const int j = t & 63, r4 = t >> 6;
  const long row = (long)blockIdx.x * 4 + r4;   // wave-uniform row
  const bf16x4* hr = (const bf16x4*)(hbf + row * 128);
  float acc = 0.f;
#pragma unroll 8
  for (int k4 = 0; k4 < 32; ++k4) {
    bf16x4 hv = hr[k4];
#pragma unroll
    for (int u = 0; u < 4; ++u)
      acc += (float)hv[u] * W2[(k4 * 4 + u) * 64 + j];
  }
  Yt[(long)j * NN + row] = (__bf16)acc;
}

// ---------------- reduce epart -> emb bf16 + sq ----------------
__global__ __launch_bounds__(256) void k_reduce2(const float* __restrict__ epart,
    __bf16* __restrict__ embb, float* __restrict__ sq) {
  const int t = threadIdx.x;
  const int c = t & 63, r4 = t >> 6;
  const long row = (long)blockIdx.x * 4 + r4;   // one wave == one row
  const long idx = row * EMB + c;
  float v = epart[idx] + epart[idx + 524288] + epart[idx + 1048576] + epart[idx + 1572864];
  __bf16 b = (__bf16)v;
  embb[idx] = b;
  float f = (float)b;
  float s = f * f;
#pragma unroll
  for (int off = 32; off >= 1; off >>= 1) s += __shfl_xor(s, off);
  if (c == 0) sq[row] = s;
}

// ---------------- big GEMM: Cpart[s] = A[:, ks] @ Bt^T[ks, :BN] ----------------
// A fp32 [8192][8192] converted inline to bf16; Bt is bf16 [BN][8192] (B transposed).
template<int BN>
__global__ __launch_bounds__(256, 2) void k_gemm(const float* __restrict__ A,
    const __bf16* __restrict__ Bt, float* __restrict__ Cpart) {
  constexpr int BM = 128, BK = 64, SPLIT = 4;
  constexpr int KSUB = NN / SPLIT;          // 2048
  constexpr int KSTEPS = KSUB / BK;         // 32
  constexpr int LDA = BK + 8;               // 72 elems: pad to break 128B-stride conflicts
  constexpr int WCOLS = BN / 64;            // 2 (BN=128) or 1 (BN=64)
  constexpr int WAVEM = (BN == 128) ? 64 : 32;
  constexpr int MT = WAVEM / 16;
  constexpr int NT = 4;
  constexpr int BCH = BN * BK / 8 / 256;    // B 16B-chunks per thread: 4 or 2

  __shared__ __bf16 Ab[BM * LDA];
  __shared__ __bf16 Bb[BN * LDA];

  const int t = threadIdx.x;
  const int mblk = blockIdx.x & 63;
  const int s = blockIdx.x >> 6;
  const long m0 = (long)mblk * BM;
  const long kbeg = (long)s * KSUB;

  const int lane = t & 63, w = t >> 6;
  const int q = lane >> 4, r16 = lane & 15;
  const int wr = w / WCOLS, wc = w % WCOLS;
  const int wrow = wr * WAVEM, wcol = wc * 64;

  // A staging: 1024 chunks of 8 floats; chunk c = t + i*256 -> row = t>>3 + 32i, col8 = t&7
  const int ar = t >> 3;
  const int ac = t & 7;
  const float* Abase = A + (m0 + ar) * (long)NN + ac * 8;

  f32x4 av0[4], av1[4];
  u32x4 bv[BCH];

  auto load_tile = [&](long kb) {
#pragma unroll
    for (int i = 0; i < 4; ++i) {
      const float* p = Abase + (long)i * 32 * NN + kb;
      av0[i] = *(const f32x4*)p;
      av1[i] = *(const f32x4*)(p + 4);
    }
#pragma unroll
    for (int i = 0; i < BCH; ++i) {
      int c = t + i * 256, n = c >> 3, cc = c & 7;
      bv[i] = *(const u32x4*)(Bt + (long)n * NN + kb + cc * 8);
    }
  };

  auto store_tile = [&]() {
#pragma unroll
    for (int i = 0; i < 4; ++i) {
      bf16x8 cv;
#pragma unroll
      for (int u = 0; u < 4; ++u) { cv[u] = (__bf16)av0[i][u]; cv[u + 4] = (__bf16)av1[i][u]; }
      *(bf16x8*)&Ab[(ar + i * 32) * LDA + ac * 8] = cv;
    }
#pragma unroll
    for (int i = 0; i < BCH; ++i) {
      int c = t + i * 256, n = c >> 3, cc = c & 7;
      *(u32x4*)&Bb[n * LDA + cc * 8] = bv[i];
    }
  };

  f32x4 zero = {0.f, 0.f, 0.f, 0.f};
  f32x4 acc[MT][NT];
#pragma unroll
  for (int mt = 0; mt < MT; ++mt)
#pragma unroll
    for (int nt = 0; nt < NT; ++nt) acc[mt][nt] = zero;

  load_tile(kbeg);
  for (int kt = 0; kt < KSTEPS; ++kt) {
    __syncthreads();
    store_tile();
    __syncthreads();
    if (kt + 1 < KSTEPS) load_tile(kbeg + (long)(kt + 1) * BK);  // prefetch overlaps MFMA
#pragma unroll
    for (int ks = 0; ks < 2; ++ks) {
      bf16x8 af[MT], bf[NT];
#pragma unroll
      for (int mt = 0; mt < MT; ++mt)
        af[mt] = *(const bf16x8*)&Ab[(wrow + mt * 16 + r16) * LDA + ks * 32 + q * 8];
#pragma unroll
      for (int nt = 0; nt < NT; ++nt)
        bf[nt] = *(const bf16x8*)&Bb[(wcol + nt * 16 + r16) * LDA + ks * 32 + q * 8];
#pragma unroll
      for (int mt = 0; mt < MT; ++mt)
#pragma unroll
        for (int nt = 0; nt < NT; ++nt)
          acc[mt][nt] = __builtin_amdgcn_mfma_f32_16x16x32_bf16(af[mt], bf[nt], acc[mt][nt], 0, 0, 0);
    }
  }

  float* Cp = Cpart + ((long)s * NN + m0) * BN;
#pragma unroll
  for (int mt = 0; mt < MT; ++mt)
#pragma unroll
    for (int nt = 0; nt < NT; ++nt)
#pragma unroll
      for (int r = 0; r < 4; ++r) {
        int gm = wrow + mt * 16 + q * 4 + r;     // C row = (lane>>4)*4 + reg
        int gn = wcol + nt * 16 + r16;           // C col = lane&15
        Cp[(long)gm * BN + gn] = acc[mt][nt][r];
      }
}

// ---------------- pass1: row sums of exp(-relu(dist)), transposed orientation ----
__global__ __launch_bounds__(256, 2) void k_pass1(const __bf16* __restrict__ emb,
    const float* __restrict__ sq, float* __restrict__ rsum) {
  constexpr int LDE = 72;
  __shared__ __bf16 Ej[128 * LDE];   // A-operand: rows j
  __shared__ __bf16 Ei[128 * LDE];   // B-operand: cols i
  __shared__ float sqi[128], sqj[128], rloc[128];
  const int t = threadIdx.x;
  const int bi = blockIdx.x & 63, bj = blockIdx.x >> 6;
  const long i0 = (long)bi * 128, j0 = (long)bj * 128;
#pragma unroll
  for (int i = 0; i < 4; ++i) {
    int c = t + i * 256, row = c >> 3, cc = c & 7;
    *(u32x4*)&Ej[row * LDE + cc * 8] = *(const u32x4*)(emb + (j0 + row) * EMB + cc * 8);
    *(u32x4*)&Ei[row * LDE + cc * 8] = *(const u32x4*)(emb + (i0 + row) * EMB + cc * 8);
  }
  if (t < 128) { sqi[t] = sq[i0 + t]; rloc[t] = 0.f; }
  else sqj[t - 128] = sq[j0 + t - 128];
  __syncthreads();

  const int lane = t & 63, w = t >> 6, q = lane >> 4, r16 = lane & 15;
  const int jr = w >> 1, ic = w & 1;   // wave tile: 64 j-rows x 64 i-cols
  f32x4 zero = {0.f, 0.f, 0.f, 0.f};
  f32x4 acc[4][4];
#pragma unroll
  for (int a = 0; a < 4; ++a)
#pragma unroll
    for (int b = 0; b < 4; ++b) acc[a][b] = zero;
#pragma unroll
  for (int ks = 0; ks < 2; ++ks) {
    bf16x8 af[4], bf[4];
#pragma unroll
    for (int jt = 0; jt < 4; ++jt)
      af[jt] = *(const bf16x8*)&Ej[(jr * 64 + jt * 16 + r16) * LDE + ks * 32 + q * 8];
#pragma unroll
    for (int it = 0; it < 4; ++it)
      bf[it] = *(const bf16x8*)&Ei[(ic * 64 + it * 16 + r16) * LDE + ks * 32 + q * 8];
#pragma unroll
    for (int jt = 0; jt < 4; ++jt)
#pragma unroll
      for (int it = 0; it < 4; ++it)
        acc[jt][it] = __builtin_amdgcn_mfma_f32_16x16x32_bf16(af[jt], bf[it], acc[jt][it], 0, 0, 0);
  }
#pragma unroll
  for (int it = 0; it < 4; ++it) {
    const int il = ic * 64 + it * 16 + r16;   // i = C col -> lane&15
    const float si = sqi[il];
    float p = 0.f;
#pragma unroll
    for (int jt = 0; jt < 4; ++jt)
#pragma unroll
      for (int r = 0; r < 4; ++r) {
        const int jl = jr * 64 + jt * 16 + q * 4 + r;
        float d = si + sqj[jl] - 2.f * acc[jt][it][r];
        d = fmaxf(d, 0.f);
        p += __expf(-d);
      }
    p += __shfl_xor(p, 16);
    p += __shfl_xor(p, 32);
    if (q == 0) atomicAdd(&rloc[il], p);
  }
  __syncthreads();
  if (t < 128) atomicAdd(&rsum[i0 + t], rloc[t]);
}

// ---------------- pass2: write out = exp(-relu(dist)) / rsum + EPS ----------------
__global__ __launch_bounds__(256, 2) void k_pass2(const __bf16* __restrict__ emb,
    const float* __restrict__ sq, const float* __restrict__ rsum,
    float* __restrict__ out) {
  constexpr int LDE = 72;
  __shared__ __bf16 Em[128 * LDE];   // A-operand: rows i
  __shared__ __bf16 En[128 * LDE];   // B-operand: cols j
  __shared__ float sqm[128], sqn[128], inv[128];
  const int t = threadIdx.x;
  const int bn = blockIdx.x & 63, bm = blockIdx.x >> 6;
  const long m0 = (long)bm * 128, n0 = (long)bn * 128;
#pragma unroll
  for (int i = 0; i < 4; ++i) {
    int c = t + i * 256, row = c >> 3, cc = c & 7;
    *(u32x4*)&Em[row * LDE + cc * 8] = *(const u32x4*)(emb + (m0 + row) * EMB + cc * 8);
    *(u32x4*)&En[row * LDE + cc * 8] = *(const u32x4*)(emb + (n0 + row) * EMB + cc * 8);
  }
  if (t < 128) { sqm[t] = sq[m0 + t]; inv[t] = 1.0f / rsum[m0 + t]; }
  else sqn[t - 128] = sq[n0 + t - 128];
  __syncthreads();

  const int lane = t & 63, w = t >> 6, q = lane >> 4, r16 = lane & 15;
  const int wr = w >> 1, wc = w & 1;
  f32x4 zero = {0.f, 0.f, 0.f, 0.f};
  f32x4 acc[4][4];
#pragma unroll
  for (int a = 0; a < 4; ++a)
#pragma unroll
    for (int b = 0; b < 4; ++b) acc[a][b] = zero;
#pragma unroll
  for (int ks = 0; ks < 2; ++ks) {
    bf16x8 af[4], bf[4];
#pragma unroll
    for (int mt = 0; mt < 4; ++mt)
      af[mt] = *(const bf16x8*)&Em[(wr * 64 + mt * 16 + r16) * LDE + ks * 32 + q * 8];
#pragma unroll
    for (int nt = 0; nt < 4; ++nt)
      bf[nt] = *(const bf16x8*)&En[(wc * 64 + nt * 16 + r16) * LDE + ks * 32 + q * 8];
#pragma unroll
    for (int mt = 0; mt < 4; ++mt)
#pragma unroll
      for (int nt = 0; nt < 4; ++nt)
        acc[mt][nt] = __builtin_amdgcn_mfma_f32_16x16x32_bf16(af[mt], bf[nt], acc[mt][nt], 0, 0, 0);
  }
#pragma unroll
  for (int mt = 0; mt < 4; ++mt)
#pragma unroll
    for (int nt = 0; nt < 4; ++nt) {
      const int jl = wc * 64 + nt * 16 + r16;
      const float sj = sqn[jl];
#pragma unroll
      for (int r = 0; r < 4; ++r) {
        const int il = wr * 64 + mt * 16 + q * 4 + r;
        float d = sqm[il] + sj - 2.f * acc[mt][nt][r];
        d = fmaxf(d, 0.f);
        float e = __expf(-d);
        out[(m0 + il) * (long)NN + n0 + jl] = fmaf(e, inv[il], 1e-10f);
      }
    }
}

extern "C" void kernel_launch(void* const* d_in, const int* in_sizes, int n_in,
                              void* d_out, int out_size, void* d_ws, size_t ws_size,
                              hipStream_t stream) {
  (void)in_sizes; (void)n_in; (void)out_size; (void)ws_size;
  const float* A  = (const float*)d_in[0];
  const float* X  = (const float*)d_in[1];
  const float* W1 = (const float*)d_in[2];
  const float* W2 = (const float*)d_in[3];
  float* out = (float*)d_out;

  char* w = (char*)d_ws;
  float*  hpart = (float*)w;                          // 16 MB [4][8192][128]
  float*  epart = (float*)w;                          // reuse:  8 MB [4][8192][64]
  __bf16* xw1t  = (__bf16*)(w + (16u << 20));         // 2 MB  [128][8192]
  __bf16* hbf   = (__bf16*)(w + (18u << 20));         // 2 MB  [8192][128]
  __bf16* ytp   = (__bf16*)(w + (20u << 20));         // 1 MB  [64][8192]
  __bf16* embb  = (__bf16*)(w + (21u << 20));         // 1 MB  [8192][64]
  float*  sq    = (float*)(w + (22u << 20));          // 32 KB
  float*  rsum  = (float*)(w + (22u << 20) + 32768);  // 32 KB

  k_zero<<<32, 256, 0, stream>>>(rsum, 8192);
  k_xw1<<<4096, 256, 0, stream>>>(X, W1, xw1t);
  k_gemm<128><<<256, 256, 0, stream>>>(A, xw1t, hpart);
  k_reduce1<<<4096, 256, 0, stream>>>(hpart, hbf);
  k_yt<<<2048, 256, 0, stream>>>(hbf, W2, ytp);
  k_gemm<64><<<256, 256, 0, stream>>>(A, ytp, epart);
  k_reduce2<<<2048, 256, 0, stream>>>(epart, embb, sq);
  k_pass1<<<4096, 256, 0, stream>>>(embb, sq, rsum);
  k_pass2<<<4096, 256, 0, stream>>>(embb, sq, rsum, out);
}

// Round 2
// 672.434 us; speedup vs baseline: 1.0125x; 1.0125x over previous
//
#include <hip/hip_runtime.h>
#include <stdint.h>

typedef float   f32x4  __attribute__((ext_vector_type(4)));
typedef __bf16  bf16x8 __attribute__((ext_vector_type(8)));
typedef uint32_t u32x4 __attribute__((ext_vector_type(4)));

#define NN 8192
#define EMB 64

// ---------------- zero rsum ----------------
__global__ void k_zero(float* __restrict__ p, int n) {
  int i = blockIdx.x * 256 + threadIdx.x;
  if (i < n) p[i] = 0.f;
}

// ---------------- XW1^T = (X @ W1)^T, bf16 [128][8192] ----------------
__global__ __launch_bounds__(256) void k_xw1(const float* __restrict__ X,
    const float* __restrict__ W1, __bf16* __restrict__ XW1t) {
  const int t = threadIdx.x;
  const int j = t & 127, r2 = t >> 7;
  const long row = (long)blockIdx.x * 2 + r2;   // wave-uniform row
  const f32x4* xr = (const f32x4*)(X + row * 256);
  float acc = 0.f;
#pragma unroll 8
  for (int k4 = 0; k4 < 64; ++k4) {
    f32x4 xv = xr[k4];
#pragma unroll
    for (int u = 0; u < 4; ++u)
      acc += xv[u] * W1[(k4 * 4 + u) * 128 + j];
  }
  XW1t[(long)j * NN + row] = (__bf16)acc;
}

// ------- fused: reduce split-K partials -> relu -> (row @ W2) -> Yt bf16 -------
__global__ __launch_bounds__(256) void k_rely(const float* __restrict__ hpart,
    const float* __restrict__ W2, __bf16* __restrict__ Yt) {
  __shared__ float hrow[4][128];
  const int t = threadIdx.x, lane = t & 63, w = t >> 6;
  const long row = (long)blockIdx.x * 4 + w;    // one wave == one row
  const long base = row * 128;
  float v0 = hpart[base + lane] + hpart[base + lane + 1048576]
           + hpart[base + lane + 2097152] + hpart[base + lane + 3145728];
  float v1 = hpart[base + lane + 64] + hpart[base + lane + 64 + 1048576]
           + hpart[base + lane + 64 + 2097152] + hpart[base + lane + 64 + 3145728];
  hrow[w][lane] = fmaxf(v0, 0.f);
  hrow[w][lane + 64] = fmaxf(v1, 0.f);
  __syncthreads();
  float acc = 0.f;
#pragma unroll 16
  for (int c = 0; c < 128; ++c)
    acc += hrow[w][c] * W2[c * 64 + lane];      // lane == output col j
  Yt[(long)lane * NN + row] = (__bf16)acc;
}

// ---------------- reduce epart -> emb bf16 + sq ----------------
__global__ __launch_bounds__(256) void k_reduce2(const float* __restrict__ epart,
    __bf16* __restrict__ embb, float* __restrict__ sq) {
  const int t = threadIdx.x;
  const int c = t & 63;
  const long row = (long)blockIdx.x * 4 + (t >> 6);   // one wave == one row
  const long idx = row * EMB + c;
  float v = epart[idx] + epart[idx + 524288] + epart[idx + 1048576] + epart[idx + 1572864];
  __bf16 b = (__bf16)v;
  embb[idx] = b;
  float f = (float)b;
  float s = f * f;
#pragma unroll
  for (int off = 32; off >= 1; off >>= 1) s += __shfl_xor(s, off);
  if (c == 0) sq[row] = s;
}

// ------- big GEMM: Cpart[s] = A[:, ks] @ Bt^T[ks, :BN], BM=64, 512 blocks -------
template<int BN>
__global__ __launch_bounds__(256, 2) void k_gemm(const float* __restrict__ A,
    const __bf16* __restrict__ Bt, float* __restrict__ Cpart) {
  constexpr int BM = 64, BK = 64, SPLIT = 4;
  constexpr int KSUB = NN / SPLIT;          // 2048
  constexpr int KSTEPS = KSUB / BK;         // 32
  constexpr int LDA = BK + 8;               // 72: pad breaks power-of-2 conflicts
  constexpr int NT = BN / 32;               // 4 (BN=128) or 2 (BN=64)
  constexpr int BCH = BN * BK / 8 / 256;    // 4 or 2

  __shared__ __bf16 Ab[BM * LDA];
  __shared__ __bf16 Bb[BN * LDA];

  const int t = threadIdx.x;
  const int mblk = blockIdx.x & 127;
  const int s = blockIdx.x >> 7;
  const long m0 = (long)mblk * BM;
  const long kbeg = (long)s * KSUB;

  const int lane = t & 63, w = t >> 6;
  const int q = lane >> 4, r16 = lane & 15;
  const int wr = w >> 1, wc = w & 1;        // 2x2 wave grid
  const int wrow = wr * 32, wcol = wc * (BN / 2);

  const int ar = t >> 3;                    // 0..31
  const int ac = t & 7;
  const float* Abase = A + (m0 + ar) * (long)NN + ac * 8;

  f32x4 av0[2], av1[2];
  u32x4 bv[BCH];

  auto load_tile = [&](long kb) {
#pragma unroll
    for (int i = 0; i < 2; ++i) {
      const float* p = Abase + (long)i * 32 * NN + kb;
      av0[i] = *(const f32x4*)p;
      av1[i] = *(const f32x4*)(p + 4);
    }
#pragma unroll
    for (int i = 0; i < BCH; ++i) {
      int c = t + i * 256, n = c >> 3, cc = c & 7;
      bv[i] = *(const u32x4*)(Bt + (long)n * NN + kb + cc * 8);
    }
  };

  auto store_tile = [&]() {
#pragma unroll
    for (int i = 0; i < 2; ++i) {
      bf16x8 cv;
#pragma unroll
      for (int u = 0; u < 4; ++u) { cv[u] = (__bf16)av0[i][u]; cv[u + 4] = (__bf16)av1[i][u]; }
      *(bf16x8*)&Ab[(ar + i * 32) * LDA + ac * 8] = cv;
    }
#pragma unroll
    for (int i = 0; i < BCH; ++i) {
      int c = t + i * 256, n = c >> 3, cc = c & 7;
      *(u32x4*)&Bb[n * LDA + cc * 8] = bv[i];
    }
  };

  f32x4 zero = {0.f, 0.f, 0.f, 0.f};
  f32x4 acc[2][NT];
#pragma unroll
  for (int mt = 0; mt < 2; ++mt)
#pragma unroll
    for (int nt = 0; nt < NT; ++nt) acc[mt][nt] = zero;

  load_tile(kbeg);
  for (int kt = 0; kt < KSTEPS; ++kt) {
    __syncthreads();
    store_tile();
    __syncthreads();
    if (kt + 1 < KSTEPS) load_tile(kbeg + (long)(kt + 1) * BK);  // prefetch
#pragma unroll
    for (int ks = 0; ks < 2; ++ks) {
      bf16x8 af[2], bf[NT];
#pragma unroll
      for (int mt = 0; mt < 2; ++mt)
        af[mt] = *(const bf16x8*)&Ab[(wrow + mt * 16 + r16) * LDA + ks * 32 + q * 8];
#pragma unroll
      for (int nt = 0; nt < NT; ++nt)
        bf[nt] = *(const bf16x8*)&Bb[(wcol + nt * 16 + r16) * LDA + ks * 32 + q * 8];
#pragma unroll
      for (int mt = 0; mt < 2; ++mt)
#pragma unroll
        for (int nt = 0; nt < NT; ++nt)
          acc[mt][nt] = __builtin_amdgcn_mfma_f32_16x16x32_bf16(af[mt], bf[nt], acc[mt][nt], 0, 0, 0);
    }
  }

  float* Cp = Cpart + ((long)s * NN + m0) * BN;
#pragma unroll
  for (int mt = 0; mt < 2; ++mt)
#pragma unroll
    for (int nt = 0; nt < NT; ++nt)
#pragma unroll
      for (int r = 0; r < 4; ++r) {
        int gm = wrow + mt * 16 + q * 4 + r;     // C row = (lane>>4)*4 + reg
        int gn = wcol + nt * 16 + r16;           // C col = lane&15
        Cp[(long)gm * BN + gn] = acc[mt][nt][r];
      }
}

// ------- pass1: row sums of exp(-relu(dist)) over triangular block pairs -------
__global__ __launch_bounds__(256, 2) void k_pass1(const __bf16* __restrict__ emb,
    const float* __restrict__ sq, float* __restrict__ rsum) {
  constexpr int LDE = 72;
  __shared__ __bf16 Ej[128 * LDE];   // A-operand: rows of j-block
  __shared__ __bf16 Ei[128 * LDE];   // B-operand: rows of i-block (C cols)
  __shared__ float sqi[128], sqj[128], rloci[128], rlocj[128];
  const int t = threadIdx.x;
  // triangular decode: pairs (bi <= bj), 2080 blocks
  const int p = blockIdx.x;
  int bj = (int)((sqrtf(8.f * (float)p + 1.f) - 1.f) * 0.5f);
  while ((bj + 1) * (bj + 2) / 2 <= p) ++bj;
  while (bj * (bj + 1) / 2 > p) --bj;
  const int bi = p - bj * (bj + 1) / 2;
  const bool diag = (bi == bj);
  const long i0 = (long)bi * 128, j0 = (long)bj * 128;
#pragma unroll
  for (int i = 0; i < 4; ++i) {
    int c = t + i * 256, row = c >> 3, cc = c & 7;
    *(u32x4*)&Ej[row * LDE + cc * 8] = *(const u32x4*)(emb + (j0 + row) * EMB + cc * 8);
    *(u32x4*)&Ei[row * LDE + cc * 8] = *(const u32x4*)(emb + (i0 + row) * EMB + cc * 8);
  }
  if (t < 128) { sqi[t] = sq[i0 + t]; rloci[t] = 0.f; }
  else { sqj[t - 128] = sq[j0 + t - 128]; rlocj[t - 128] = 0.f; }
  __syncthreads();

  const int lane = t & 63, w = t >> 6, q = lane >> 4, r16 = lane & 15;
  const int jr = w >> 1, ic = w & 1;   // wave tile: 64 j-rows x 64 i-cols
  f32x4 zero = {0.f, 0.f, 0.f, 0.f};
  f32x4 acc[4][4];
#pragma unroll
  for (int a = 0; a < 4; ++a)
#pragma unroll
    for (int b = 0; b < 4; ++b) acc[a][b] = zero;
#pragma unroll
  for (int ks = 0; ks < 2; ++ks) {
    bf16x8 af[4], bf[4];
#pragma unroll
    for (int jt = 0; jt < 4; ++jt)
      af[jt] = *(const bf16x8*)&Ej[(jr * 64 + jt * 16 + r16) * LDE + ks * 32 + q * 8];
#pragma unroll
    for (int it = 0; it < 4; ++it)
      bf[it] = *(const bf16x8*)&Ei[(ic * 64 + it * 16 + r16) * LDE + ks * 32 + q * 8];
#pragma unroll
    for (int jt = 0; jt < 4; ++jt)
#pragma unroll
      for (int it = 0; it < 4; ++it)
        acc[jt][it] = __builtin_amdgcn_mfma_f32_16x16x32_bf16(af[jt], bf[it], acc[jt][it], 0, 0, 0);
  }

  float colp[4] = {0.f, 0.f, 0.f, 0.f};  // per it: sums over tile rows (j)
  float rowp[4][4];                      // per (jt,r): sums over tile cols (i)
#pragma unroll
  for (int jt = 0; jt < 4; ++jt)
#pragma unroll
    for (int r = 0; r < 4; ++r) rowp[jt][r] = 0.f;
#pragma unroll
  for (int it = 0; it < 4; ++it) {
    const int il = ic * 64 + it * 16 + r16;
    const float si = sqi[il];
#pragma unroll
    for (int jt = 0; jt < 4; ++jt)
#pragma unroll
      for (int r = 0; r < 4; ++r) {
        const int jl = jr * 64 + jt * 16 + q * 4 + r;
        float d = fmaxf(si + sqj[jl] - 2.f * acc[jt][it][r], 0.f);
        float e = __expf(-d);
        colp[it] += e;
        rowp[jt][r] += e;
      }
  }
  // column sums -> rsum of i-block
#pragma unroll
  for (int it = 0; it < 4; ++it) {
    float pp = colp[it];
    pp += __shfl_xor(pp, 16);
    pp += __shfl_xor(pp, 32);
    if (q == 0) atomicAdd(&rloci[ic * 64 + it * 16 + r16], pp);
  }
  // row sums -> rsum of j-block (skip on diagonal to avoid double count)
  if (!diag) {
#pragma unroll
    for (int jt = 0; jt < 4; ++jt)
#pragma unroll
      for (int r = 0; r < 4; ++r) {
        float pp = rowp[jt][r];
        pp += __shfl_xor(pp, 1);
        pp += __shfl_xor(pp, 2);
        pp += __shfl_xor(pp, 4);
        pp += __shfl_xor(pp, 8);
        if (r16 == 0) atomicAdd(&rlocj[jr * 64 + jt * 16 + q * 4 + r], pp);
      }
  }
  __syncthreads();
  if (t < 128) {
    atomicAdd(&rsum[i0 + t], rloci[t]);
    if (!diag) atomicAdd(&rsum[j0 + t], rlocj[t]);
  }
}

// ---------------- pass2: write out = exp(-relu(dist)) / rsum + EPS ----------------
__global__ __launch_bounds__(256, 2) void k_pass2(const __bf16* __restrict__ emb,
    const float* __restrict__ sq, const float* __restrict__ rsum,
    float* __restrict__ out) {
  constexpr int LDE = 72;
  __shared__ __bf16 Em[128 * LDE];
  __shared__ __bf16 En[128 * LDE];
  __shared__ float sqm[128], sqn[128], inv[128];
  const int t = threadIdx.x;
  const int bn = blockIdx.x & 63, bm = blockIdx.x >> 6;
  const long m0 = (long)bm * 128, n0 = (long)bn * 128;
#pragma unroll
  for (int i = 0; i < 4; ++i) {
    int c = t + i * 256, row = c >> 3, cc = c & 7;
    *(u32x4*)&Em[row * LDE + cc * 8] = *(const u32x4*)(emb + (m0 + row) * EMB + cc * 8);
    *(u32x4*)&En[row * LDE + cc * 8] = *(const u32x4*)(emb + (n0 + row) * EMB + cc * 8);
  }
  if (t < 128) { sqm[t] = sq[m0 + t]; inv[t] = 1.0f / rsum[m0 + t]; }
  else sqn[t - 128] = sq[n0 + t - 128];
  __syncthreads();

  const int lane = t & 63, w = t >> 6, q = lane >> 4, r16 = lane & 15;
  const int wr = w >> 1, wc = w & 1;
  f32x4 zero = {0.f, 0.f, 0.f, 0.f};
  f32x4 acc[4][4];
#pragma unroll
  for (int a = 0; a < 4; ++a)
#pragma unroll
    for (int b = 0; b < 4; ++b) acc[a][b] = zero;
#pragma unroll
  for (int ks = 0; ks < 2; ++ks) {
    bf16x8 af[4], bf[4];
#pragma unroll
    for (int mt = 0; mt < 4; ++mt)
      af[mt] = *(const bf16x8*)&Em[(wr * 64 + mt * 16 + r16) * LDE + ks * 32 + q * 8];
#pragma unroll
    for (int nt = 0; nt < 4; ++nt)
      bf[nt] = *(const bf16x8*)&En[(wc * 64 + nt * 16 + r16) * LDE + ks * 32 + q * 8];
#pragma unroll
    for (int mt = 0; mt < 4; ++mt)
#pragma unroll
      for (int nt = 0; nt < 4; ++nt)
        acc[mt][nt] = __builtin_amdgcn_mfma_f32_16x16x32_bf16(af[mt], bf[nt], acc[mt][nt], 0, 0, 0);
  }
#pragma unroll
  for (int mt = 0; mt < 4; ++mt)
#pragma unroll
    for (int nt = 0; nt < 4; ++nt) {
      const int jl = wc * 64 + nt * 16 + r16;
      const float sj = sqn[jl];
#pragma unroll
      for (int r = 0; r < 4; ++r) {
        const int il = wr * 64 + mt * 16 + q * 4 + r;
        float d = fmaxf(sqm[il] + sj - 2.f * acc[mt][nt][r], 0.f);
        float e = __expf(-d);
        out[(m0 + il) * (long)NN + n0 + jl] = fmaf(e, inv[il], 1e-10f);
      }
    }
}

extern "C" void kernel_launch(void* const* d_in, const int* in_sizes, int n_in,
                              void* d_out, int out_size, void* d_ws, size_t ws_size,
                              hipStream_t stream) {
  (void)in_sizes; (void)n_in; (void)out_size; (void)ws_size;
  const float* A  = (const float*)d_in[0];
  const float* X  = (const float*)d_in[1];
  const float* W1 = (const float*)d_in[2];
  const float* W2 = (const float*)d_in[3];
  float* out = (float*)d_out;

  char* w = (char*)d_ws;
  float*  hpart = (float*)w;                          // 16 MB [4][8192][128]
  float*  epart = (float*)w;                          // reuse:  8 MB [4][8192][64]
  __bf16* xw1t  = (__bf16*)(w + (16u << 20));         // 2 MB  [128][8192]
  __bf16* ytp   = (__bf16*)(w + (18u << 20));         // 1 MB  [64][8192]
  __bf16* embb  = (__bf16*)(w + (19u << 20));         // 1 MB  [8192][64]
  float*  sq    = (float*)(w + (20u << 20));          // 32 KB
  float*  rsum  = (float*)(w + (20u << 20) + 32768);  // 32 KB

  k_zero<<<32, 256, 0, stream>>>(rsum, 8192);
  k_xw1<<<4096, 256, 0, stream>>>(X, W1, xw1t);
  k_gemm<128><<<512, 256, 0, stream>>>(A, xw1t, hpart);
  k_rely<<<2048, 256, 0, stream>>>(hpart, W2, ytp);
  k_gemm<64><<<512, 256, 0, stream>>>(A, ytp, epart);
  k_reduce2<<<2048, 256, 0, stream>>>(epart, embb, sq);
  k_pass1<<<2080, 256, 0, stream>>>(embb, sq, rsum);
  k_pass2<<<4096, 256, 0, stream>>>(embb, sq, rsum, out);
}

// Round 3
// 651.125 us; speedup vs baseline: 1.0456x; 1.0327x over previous
//
#include <hip/hip_runtime.h>
#include <stdint.h>

typedef float   f32x4  __attribute__((ext_vector_type(4)));
typedef float   f32x2  __attribute__((ext_vector_type(2)));
typedef __bf16  bf16x8 __attribute__((ext_vector_type(8)));
typedef uint32_t u32x4 __attribute__((ext_vector_type(4)));
typedef uint32_t u32x2 __attribute__((ext_vector_type(2)));

#define NN 8192
#define EMB 64
#define A_SCALE 8192.0f          // A*2^13 -> [0,1): e4m3 normal range
#define A_UNSCALE (1.0f/8192.0f)

// ---------------- zero rsum ----------------
__global__ void k_zero(float* __restrict__ p, int n) {
  int i = blockIdx.x * 256 + threadIdx.x;
  if (i < n) p[i] = 0.f;
}

// ---------------- XW1^T = (X @ W1)^T, bf16 [128][8192] ----------------
__global__ __launch_bounds__(256) void k_xw1(const float* __restrict__ X,
    const float* __restrict__ W1, __bf16* __restrict__ XW1t) {
  const int t = threadIdx.x;
  const int j = t & 127, r2 = t >> 7;
  const long row = (long)blockIdx.x * 2 + r2;   // wave-uniform row
  const f32x4* xr = (const f32x4*)(X + row * 256);
  float acc = 0.f;
#pragma unroll 8
  for (int k4 = 0; k4 < 64; ++k4) {
    f32x4 xv = xr[k4];
#pragma unroll
    for (int u = 0; u < 4; ++u)
      acc += xv[u] * W1[(k4 * 4 + u) * 128 + j];
  }
  XW1t[(long)j * NN + row] = (__bf16)acc;
}

// ------- fused: reduce split-K bf16 partials -> relu -> (row @ W2) -> Yt bf16 ----
__global__ __launch_bounds__(256) void k_rely(const __bf16* __restrict__ hp,
    const float* __restrict__ W2, __bf16* __restrict__ Yt) {
  __shared__ float hrow[4][128];
  const int t = threadIdx.x, lane = t & 63, w = t >> 6;
  const long row = (long)blockIdx.x * 4 + w;    // one wave == one row
  const long base = row * 128;
  float v0 = (float)hp[base + lane] + (float)hp[base + lane + 1048576]
           + (float)hp[base + lane + 2097152] + (float)hp[base + lane + 3145728];
  float v1 = (float)hp[base + lane + 64] + (float)hp[base + lane + 64 + 1048576]
           + (float)hp[base + lane + 64 + 2097152] + (float)hp[base + lane + 64 + 3145728];
  hrow[w][lane] = fmaxf(v0, 0.f);
  hrow[w][lane + 64] = fmaxf(v1, 0.f);
  __syncthreads();
  float acc = 0.f;
#pragma unroll 16
  for (int c = 0; c < 128; ++c)
    acc += hrow[w][c] * W2[c * 64 + lane];      // lane == output col j
  Yt[(long)lane * NN + row] = (__bf16)acc;
}

// ------- reduce epart (bf16, scaled by 2^13) -> emb bf16 + sq ----------------
__global__ __launch_bounds__(256) void k_reduce2(const __bf16* __restrict__ ep,
    __bf16* __restrict__ embb, float* __restrict__ sq) {
  const int t = threadIdx.x;
  const int c = t & 63;
  const long row = (long)blockIdx.x * 4 + (t >> 6);   // one wave == one row
  const long idx = row * EMB + c;
  float v = ((float)ep[idx] + (float)ep[idx + 524288]
           + (float)ep[idx + 1048576] + (float)ep[idx + 1572864]) * A_UNSCALE;
  __bf16 b = (__bf16)v;
  embb[idx] = b;
  float f = (float)b;
  float s = f * f;
#pragma unroll
  for (int off = 32; off >= 1; off >>= 1) s += __shfl_xor(s, off);
  if (c == 0) sq[row] = s;
}

// ------- gemm1: hpart[s] = A[:,ks] @ XW1t^T, also emits A8 = fp8(A*2^13) -------
__global__ __launch_bounds__(256, 2) void k_gemm1(const float* __restrict__ A,
    const __bf16* __restrict__ Bt, __bf16* __restrict__ Cpart,
    unsigned char* __restrict__ A8) {
  constexpr int BM = 64, BK = 64, BN = 128;
  constexpr int KSUB = 2048, KSTEPS = 32;
  constexpr int LDA = BK + 8;               // 72: pad breaks power-of-2 conflicts
  constexpr int NT = 4, BCH = 4;

  __shared__ __bf16 Ab[BM * LDA];
  __shared__ __bf16 Bb[BN * LDA];

  const int t = threadIdx.x;
  const int mblk = blockIdx.x & 127;
  const int s = blockIdx.x >> 7;
  const long m0 = (long)mblk * BM;
  const long kbeg = (long)s * KSUB;

  const int lane = t & 63, w = t >> 6;
  const int q = lane >> 4, r16 = lane & 15;
  const int wr = w >> 1, wc = w & 1;        // 2x2 wave grid
  const int wrow = wr * 32, wcol = wc * 64;

  const int ar = t >> 3;                    // 0..31
  const int ac = t & 7;
  const float* Abase = A + (m0 + ar) * (long)NN + ac * 8;

  f32x4 av0[2], av1[2];
  u32x4 bv[BCH];
  long pend_kb = kbeg;

  auto load_tile = [&](long kb) {
    pend_kb = kb;
#pragma unroll
    for (int i = 0; i < 2; ++i) {
      const float* p = Abase + (long)i * 32 * NN + kb;
      av0[i] = *(const f32x4*)p;
      av1[i] = *(const f32x4*)(p + 4);
    }
#pragma unroll
    for (int i = 0; i < BCH; ++i) {
      int c = t + i * 256, n = c >> 3, cc = c & 7;
      bv[i] = *(const u32x4*)(Bt + (long)n * NN + kb + cc * 8);
    }
  };

  auto store_tile = [&]() {
#pragma unroll
    for (int i = 0; i < 2; ++i) {
      // fp8 side-product (scaled into e4m3 normal range)
      int lo = __builtin_amdgcn_cvt_pk_fp8_f32(av0[i][0] * A_SCALE, av0[i][1] * A_SCALE, 0, false);
      lo     = __builtin_amdgcn_cvt_pk_fp8_f32(av0[i][2] * A_SCALE, av0[i][3] * A_SCALE, lo, true);
      int hi = __builtin_amdgcn_cvt_pk_fp8_f32(av1[i][0] * A_SCALE, av1[i][1] * A_SCALE, 0, false);
      hi     = __builtin_amdgcn_cvt_pk_fp8_f32(av1[i][2] * A_SCALE, av1[i][3] * A_SCALE, hi, true);
      u32x2 p8; p8[0] = (uint32_t)lo; p8[1] = (uint32_t)hi;
      *(u32x2*)&A8[(m0 + ar + i * 32) * (long)NN + pend_kb + ac * 8] = p8;
      // bf16 LDS tile for MFMA
      bf16x8 cv;
#pragma unroll
      for (int u = 0; u < 4; ++u) { cv[u] = (__bf16)av0[i][u]; cv[u + 4] = (__bf16)av1[i][u]; }
      *(bf16x8*)&Ab[(ar + i * 32) * LDA + ac * 8] = cv;
    }
#pragma unroll
    for (int i = 0; i < BCH; ++i) {
      int c = t + i * 256, n = c >> 3, cc = c & 7;
      *(u32x4*)&Bb[n * LDA + cc * 8] = bv[i];
    }
  };

  f32x4 zero = {0.f, 0.f, 0.f, 0.f};
  f32x4 acc[2][NT];
#pragma unroll
  for (int mt = 0; mt < 2; ++mt)
#pragma unroll
    for (int nt = 0; nt < NT; ++nt) acc[mt][nt] = zero;

  load_tile(kbeg);
  for (int kt = 0; kt < KSTEPS; ++kt) {
    __syncthreads();
    store_tile();
    __syncthreads();
    if (kt + 1 < KSTEPS) load_tile(kbeg + (long)(kt + 1) * BK);  // prefetch
#pragma unroll
    for (int ks = 0; ks < 2; ++ks) {
      bf16x8 af[2], bf[NT];
#pragma unroll
      for (int mt = 0; mt < 2; ++mt)
        af[mt] = *(const bf16x8*)&Ab[(wrow + mt * 16 + r16) * LDA + ks * 32 + q * 8];
#pragma unroll
      for (int nt = 0; nt < NT; ++nt)
        bf[nt] = *(const bf16x8*)&Bb[(wcol + nt * 16 + r16) * LDA + ks * 32 + q * 8];
#pragma unroll
      for (int mt = 0; mt < 2; ++mt)
#pragma unroll
        for (int nt = 0; nt < NT; ++nt)
          acc[mt][nt] = __builtin_amdgcn_mfma_f32_16x16x32_bf16(af[mt], bf[nt], acc[mt][nt], 0, 0, 0);
    }
  }

  __bf16* Cp = Cpart + ((long)s * NN + m0) * BN;
#pragma unroll
  for (int mt = 0; mt < 2; ++mt)
#pragma unroll
    for (int nt = 0; nt < NT; ++nt)
#pragma unroll
      for (int r = 0; r < 4; ++r) {
        int gm = wrow + mt * 16 + q * 4 + r;     // C row = (lane>>4)*4 + reg
        int gn = wcol + nt * 16 + r16;           // C col = lane&15
        Cp[(long)gm * BN + gn] = (__bf16)acc[mt][nt][r];
      }
}

// ------- gemm2: epart[s] = A8[:,ks] @ Yt^T  (fp8 A -> bf16 MFMA) -------
__global__ __launch_bounds__(256, 2) void k_gemm2(const unsigned char* __restrict__ A8,
    const __bf16* __restrict__ Bt, __bf16* __restrict__ Cpart) {
  constexpr int BM = 64, BK = 64, BN = 64;
  constexpr int KSUB = 2048, KSTEPS = 32;
  constexpr int LDA = BK + 8;
  constexpr int NT = 2, BCH = 2;

  __shared__ __bf16 Ab[BM * LDA];
  __shared__ __bf16 Bb[BN * LDA];

  const int t = threadIdx.x;
  const int mblk = blockIdx.x & 127;
  const int s = blockIdx.x >> 7;
  const long m0 = (long)mblk * BM;
  const long kbeg = (long)s * KSUB;

  const int lane = t & 63, w = t >> 6;
  const int q = lane >> 4, r16 = lane & 15;
  const int wr = w >> 1, wc = w & 1;
  const int wrow = wr * 32, wcol = wc * 32;

  const int ar = t >> 2;                    // 0..63
  const int ac4 = t & 3;                    // 16-byte chunk within row
  const unsigned char* Abase = A8 + (m0 + ar) * (long)NN + ac4 * 16;

  u32x4 a8v;
  u32x4 bv[BCH];

  auto load_tile = [&](long kb) {
    a8v = *(const u32x4*)(Abase + kb);
#pragma unroll
    for (int i = 0; i < BCH; ++i) {
      int c = t + i * 256, n = c >> 3, cc = c & 7;
      bv[i] = *(const u32x4*)(Bt + (long)n * NN + kb + cc * 8);
    }
  };

  auto store_tile = [&]() {
    bf16x8 c0, c1;
#pragma unroll
    for (int d = 0; d < 2; ++d) {
      f32x2 f01 = __builtin_amdgcn_cvt_pk_f32_fp8((int)a8v[d], false);
      f32x2 f23 = __builtin_amdgcn_cvt_pk_f32_fp8((int)a8v[d], true);
      c0[d * 4 + 0] = (__bf16)f01[0]; c0[d * 4 + 1] = (__bf16)f01[1];
      c0[d * 4 + 2] = (__bf16)f23[0]; c0[d * 4 + 3] = (__bf16)f23[1];
    }
#pragma unroll
    for (int d = 2; d < 4; ++d) {
      f32x2 f01 = __builtin_amdgcn_cvt_pk_f32_fp8((int)a8v[d], false);
      f32x2 f23 = __builtin_amdgcn_cvt_pk_f32_fp8((int)a8v[d], true);
      c1[(d - 2) * 4 + 0] = (__bf16)f01[0]; c1[(d - 2) * 4 + 1] = (__bf16)f01[1];
      c1[(d - 2) * 4 + 2] = (__bf16)f23[0]; c1[(d - 2) * 4 + 3] = (__bf16)f23[1];
    }
    *(bf16x8*)&Ab[ar * LDA + ac4 * 16] = c0;
    *(bf16x8*)&Ab[ar * LDA + ac4 * 16 + 8] = c1;
#pragma unroll
    for (int i = 0; i < BCH; ++i) {
      int c = t + i * 256, n = c >> 3, cc = c & 7;
      *(u32x4*)&Bb[n * LDA + cc * 8] = bv[i];
    }
  };

  f32x4 zero = {0.f, 0.f, 0.f, 0.f};
  f32x4 acc[2][NT];
#pragma unroll
  for (int mt = 0; mt < 2; ++mt)
#pragma unroll
    for (int nt = 0; nt < NT; ++nt) acc[mt][nt] = zero;

  load_tile(kbeg);
  for (int kt = 0; kt < KSTEPS; ++kt) {
    __syncthreads();
    store_tile();
    __syncthreads();
    if (kt + 1 < KSTEPS) load_tile(kbeg + (long)(kt + 1) * BK);
#pragma unroll
    for (int ks = 0; ks < 2; ++ks) {
      bf16x8 af[2], bf[NT];
#pragma unroll
      for (int mt = 0; mt < 2; ++mt)
        af[mt] = *(const bf16x8*)&Ab[(wrow + mt * 16 + r16) * LDA + ks * 32 + q * 8];
#pragma unroll
      for (int nt = 0; nt < NT; ++nt)
        bf[nt] = *(const bf16x8*)&Bb[(wcol + nt * 16 + r16) * LDA + ks * 32 + q * 8];
#pragma unroll
      for (int mt = 0; mt < 2; ++mt)
#pragma unroll
        for (int nt = 0; nt < NT; ++nt)
          acc[mt][nt] = __builtin_amdgcn_mfma_f32_16x16x32_bf16(af[mt], bf[nt], acc[mt][nt], 0, 0, 0);
    }
  }

  __bf16* Cp = Cpart + ((long)s * NN + m0) * BN;
#pragma unroll
  for (int mt = 0; mt < 2; ++mt)
#pragma unroll
    for (int nt = 0; nt < NT; ++nt)
#pragma unroll
      for (int r = 0; r < 4; ++r) {
        int gm = wrow + mt * 16 + q * 4 + r;
        int gn = wcol + nt * 16 + r16;
        Cp[(long)gm * BN + gn] = (__bf16)acc[mt][nt][r];
      }
}

// ------- pass1: row sums of exp(-relu(dist)) over triangular block pairs -------
__global__ __launch_bounds__(256, 2) void k_pass1(const __bf16* __restrict__ emb,
    const float* __restrict__ sq, float* __restrict__ rsum) {
  constexpr int LDE = 72;
  __shared__ __bf16 Ej[128 * LDE];   // A-operand: rows of j-block
  __shared__ __bf16 Ei[128 * LDE];   // B-operand: rows of i-block (C cols)
  __shared__ float sqi[128], sqj[128], rloci[128], rlocj[128];
  const int t = threadIdx.x;
  const int p = blockIdx.x;
  int bj = (int)((sqrtf(8.f * (float)p + 1.f) - 1.f) * 0.5f);
  while ((bj + 1) * (bj + 2) / 2 <= p) ++bj;
  while (bj * (bj + 1) / 2 > p) --bj;
  const int bi = p - bj * (bj + 1) / 2;
  const bool diag = (bi == bj);
  const long i0 = (long)bi * 128, j0 = (long)bj * 128;
#pragma unroll
  for (int i = 0; i < 4; ++i) {
    int c = t + i * 256, row = c >> 3, cc = c & 7;
    *(u32x4*)&Ej[row * LDE + cc * 8] = *(const u32x4*)(emb + (j0 + row) * EMB + cc * 8);
    *(u32x4*)&Ei[row * LDE + cc * 8] = *(const u32x4*)(emb + (i0 + row) * EMB + cc * 8);
  }
  if (t < 128) { sqi[t] = sq[i0 + t]; rloci[t] = 0.f; }
  else { sqj[t - 128] = sq[j0 + t - 128]; rlocj[t - 128] = 0.f; }
  __syncthreads();

  const int lane = t & 63, w = t >> 6, q = lane >> 4, r16 = lane & 15;
  const int jr = w >> 1, ic = w & 1;   // wave tile: 64 j-rows x 64 i-cols
  f32x4 zero = {0.f, 0.f, 0.f, 0.f};
  f32x4 acc[4][4];
#pragma unroll
  for (int a = 0; a < 4; ++a)
#pragma unroll
    for (int b = 0; b < 4; ++b) acc[a][b] = zero;
#pragma unroll
  for (int ks = 0; ks < 2; ++ks) {
    bf16x8 af[4], bf[4];
#pragma unroll
    for (int jt = 0; jt < 4; ++jt)
      af[jt] = *(const bf16x8*)&Ej[(jr * 64 + jt * 16 + r16) * LDE + ks * 32 + q * 8];
#pragma unroll
    for (int it = 0; it < 4; ++it)
      bf[it] = *(const bf16x8*)&Ei[(ic * 64 + it * 16 + r16) * LDE + ks * 32 + q * 8];
#pragma unroll
    for (int jt = 0; jt < 4; ++jt)
#pragma unroll
      for (int it = 0; it < 4; ++it)
        acc[jt][it] = __builtin_amdgcn_mfma_f32_16x16x32_bf16(af[jt], bf[it], acc[jt][it], 0, 0, 0);
  }

  float colp[4] = {0.f, 0.f, 0.f, 0.f};
  float rowp[4][4];
#pragma unroll
  for (int jt = 0; jt < 4; ++jt)
#pragma unroll
    for (int r = 0; r < 4; ++r) rowp[jt][r] = 0.f;
#pragma unroll
  for (int it = 0; it < 4; ++it) {
    const int il = ic * 64 + it * 16 + r16;
    const float si = sqi[il];
#pragma unroll
    for (int jt = 0; jt < 4; ++jt)
#pragma unroll
      for (int r = 0; r < 4; ++r) {
        const int jl = jr * 64 + jt * 16 + q * 4 + r;
        float d = fmaxf(si + sqj[jl] - 2.f * acc[jt][it][r], 0.f);
        float e = __expf(-d);
        colp[it] += e;
        rowp[jt][r] += e;
      }
  }
#pragma unroll
  for (int it = 0; it < 4; ++it) {
    float pp = colp[it];
    pp += __shfl_xor(pp, 16);
    pp += __shfl_xor(pp, 32);
    if (q == 0) atomicAdd(&rloci[ic * 64 + it * 16 + r16], pp);
  }
  if (!diag) {
#pragma unroll
    for (int jt = 0; jt < 4; ++jt)
#pragma unroll
      for (int r = 0; r < 4; ++r) {
        float pp = rowp[jt][r];
        pp += __shfl_xor(pp, 1);
        pp += __shfl_xor(pp, 2);
        pp += __shfl_xor(pp, 4);
        pp += __shfl_xor(pp, 8);
        if (r16 == 0) atomicAdd(&rlocj[jr * 64 + jt * 16 + q * 4 + r], pp);
      }
  }
  __syncthreads();
  if (t < 128) {
    atomicAdd(&rsum[i0 + t], rloci[t]);
    if (!diag) atomicAdd(&rsum[j0 + t], rlocj[t]);
  }
}

// ---------------- pass2: write out = exp(-relu(dist)) / rsum + EPS ----------------
__global__ __launch_bounds__(256, 2) void k_pass2(const __bf16* __restrict__ emb,
    const float* __restrict__ sq, const float* __restrict__ rsum,
    float* __restrict__ out) {
  constexpr int LDE = 72;
  __shared__ __bf16 Em[128 * LDE];
  __shared__ __bf16 En[128 * LDE];
  __shared__ float sqm[128], sqn[128], inv[128];
  const int t = threadIdx.x;
  const int bn = blockIdx.x & 63, bm = blockIdx.x >> 6;
  const long m0 = (long)bm * 128, n0 = (long)bn * 128;
#pragma unroll
  for (int i = 0; i < 4; ++i) {
    int c = t + i * 256, row = c >> 3, cc = c & 7;
    *(u32x4*)&Em[row * LDE + cc * 8] = *(const u32x4*)(emb + (m0 + row) * EMB + cc * 8);
    *(u32x4*)&En[row * LDE + cc * 8] = *(const u32x4*)(emb + (n0 + row) * EMB + cc * 8);
  }
  if (t < 128) { sqm[t] = sq[m0 + t]; inv[t] = 1.0f / rsum[m0 + t]; }
  else sqn[t - 128] = sq[n0 + t - 128];
  __syncthreads();

  const int lane = t & 63, w = t >> 6, q = lane >> 4, r16 = lane & 15;
  const int wr = w >> 1, wc = w & 1;
  f32x4 zero = {0.f, 0.f, 0.f, 0.f};
  f32x4 acc[4][4];
#pragma unroll
  for (int a = 0; a < 4; ++a)
#pragma unroll
    for (int b = 0; b < 4; ++b) acc[a][b] = zero;
#pragma unroll
  for (int ks = 0; ks < 2; ++ks) {
    bf16x8 af[4], bf[4];
#pragma unroll
    for (int mt = 0; mt < 4; ++mt)
      af[mt] = *(const bf16x8*)&Em[(wr * 64 + mt * 16 + r16) * LDE + ks * 32 + q * 8];
#pragma unroll
    for (int nt = 0; nt < 4; ++nt)
      bf[nt] = *(const bf16x8*)&En[(wc * 64 + nt * 16 + r16) * LDE + ks * 32 + q * 8];
#pragma unroll
    for (int mt = 0; mt < 4; ++mt)
#pragma unroll
      for (int nt = 0; nt < 4; ++nt)
        acc[mt][nt] = __builtin_amdgcn_mfma_f32_16x16x32_bf16(af[mt], bf[nt], acc[mt][nt], 0, 0, 0);
  }
#pragma unroll
  for (int mt = 0; mt < 4; ++mt)
#pragma unroll
    for (int nt = 0; nt < 4; ++nt) {
      const int jl = wc * 64 + nt * 16 + r16;
      const float sj = sqn[jl];
#pragma unroll
      for (int r = 0; r < 4; ++r) {
        const int il = wr * 64 + mt * 16 + q * 4 + r;
        float d = fmaxf(sqm[il] + sj - 2.f * acc[mt][nt][r], 0.f);
        float e = __expf(-d);
        out[(m0 + il) * (long)NN + n0 + jl] = fmaf(e, inv[il], 1e-10f);
      }
    }
}

extern "C" void kernel_launch(void* const* d_in, const int* in_sizes, int n_in,
                              void* d_out, int out_size, void* d_ws, size_t ws_size,
                              hipStream_t stream) {
  (void)in_sizes; (void)n_in; (void)out_size; (void)ws_size;
  const float* A  = (const float*)d_in[0];
  const float* X  = (const float*)d_in[1];
  const float* W1 = (const float*)d_in[2];
  const float* W2 = (const float*)d_in[3];
  float* out = (float*)d_out;

  char* w = (char*)d_ws;
  __bf16* hpartb = (__bf16*)w;                        //  8 MB [4][8192][128] bf16
  __bf16* epartb = (__bf16*)w;                        // reuse: 4 MB [4][8192][64]
  unsigned char* A8 = (unsigned char*)(w + (16u << 20));  // 64 MB fp8 [8192][8192]
  __bf16* xw1t  = (__bf16*)(w + (80u << 20));         // 2 MB  [128][8192]
  __bf16* ytp   = (__bf16*)(w + (82u << 20));         // 1 MB  [64][8192]
  __bf16* embb  = (__bf16*)(w + (83u << 20));         // 1 MB  [8192][64]
  float*  sq    = (float*)(w + (84u << 20));          // 32 KB
  float*  rsum  = (float*)(w + (84u << 20) + 32768);  // 32 KB

  k_zero<<<32, 256, 0, stream>>>(rsum, 8192);
  k_xw1<<<4096, 256, 0, stream>>>(X, W1, xw1t);
  k_gemm1<<<512, 256, 0, stream>>>(A, xw1t, hpartb, A8);
  k_rely<<<2048, 256, 0, stream>>>(hpartb, W2, ytp);
  k_gemm2<<<512, 256, 0, stream>>>(A8, ytp, epartb);
  k_reduce2<<<2048, 256, 0, stream>>>(epartb, embb, sq);
  k_pass1<<<2080, 256, 0, stream>>>(embb, sq, rsum);
  k_pass2<<<4096, 256, 0, stream>>>(embb, sq, rsum, out);
}

// Round 4
// 641.380 us; speedup vs baseline: 1.0615x; 1.0152x over previous
//
#include <hip/hip_runtime.h>
#include <stdint.h>

typedef float   f32x4  __attribute__((ext_vector_type(4)));
typedef float   f32x2  __attribute__((ext_vector_type(2)));
typedef __bf16  bf16x8 __attribute__((ext_vector_type(8)));
typedef uint32_t u32x4 __attribute__((ext_vector_type(4)));
typedef uint32_t u32x2 __attribute__((ext_vector_type(2)));

#define NN 8192
#define EMB 64
#define A_SCALE 8192.0f          // A*2^13 -> [0,1): e4m3 normal range
#define A_UNSCALE (1.0f/8192.0f)
#define SPLIT 8

// ------- XW1^T = (X @ W1)^T, bf16 [128][8192]; also zeroes rsum -------
__global__ __launch_bounds__(256) void k_xw1(const float* __restrict__ X,
    const float* __restrict__ W1, __bf16* __restrict__ XW1t,
    float* __restrict__ rsum) {
  if (blockIdx.x < 32) rsum[blockIdx.x * 256 + threadIdx.x] = 0.f;
  const int t = threadIdx.x;
  const int j = t & 127, r2 = t >> 7;
  const long row = (long)blockIdx.x * 2 + r2;   // wave-uniform row
  const f32x4* xr = (const f32x4*)(X + row * 256);
  float acc = 0.f;
#pragma unroll 8
  for (int k4 = 0; k4 < 64; ++k4) {
    f32x4 xv = xr[k4];
#pragma unroll
    for (int u = 0; u < 4; ++u)
      acc += xv[u] * W1[(k4 * 4 + u) * 128 + j];
  }
  XW1t[(long)j * NN + row] = (__bf16)acc;
}

// ------- fused: reduce split-K bf16 partials -> relu -> (row @ W2) -> Yt bf16 ----
__global__ __launch_bounds__(256) void k_rely(const __bf16* __restrict__ hp,
    const float* __restrict__ W2, __bf16* __restrict__ Yt) {
  __shared__ float hrow[4][128];
  const int t = threadIdx.x, lane = t & 63, w = t >> 6;
  const long row = (long)blockIdx.x * 4 + w;    // one wave == one row
  const long base = row * 128;
  float v0 = 0.f, v1 = 0.f;
#pragma unroll
  for (int sI = 0; sI < SPLIT; ++sI) {
    v0 += (float)hp[base + lane + (long)sI * 1048576];
    v1 += (float)hp[base + lane + 64 + (long)sI * 1048576];
  }
  hrow[w][lane] = fmaxf(v0, 0.f);
  hrow[w][lane + 64] = fmaxf(v1, 0.f);
  __syncthreads();
  float acc = 0.f;
#pragma unroll 16
  for (int c = 0; c < 128; ++c)
    acc += hrow[w][c] * W2[c * 64 + lane];      // lane == output col j
  Yt[(long)lane * NN + row] = (__bf16)acc;
}

// ------- reduce epart (bf16, scaled by 2^13) -> emb bf16 + sq ----------------
__global__ __launch_bounds__(256) void k_reduce2(const __bf16* __restrict__ ep,
    __bf16* __restrict__ embb, float* __restrict__ sq) {
  const int t = threadIdx.x;
  const int c = t & 63;
  const long row = (long)blockIdx.x * 4 + (t >> 6);   // one wave == one row
  const long idx = row * EMB + c;
  float v = 0.f;
#pragma unroll
  for (int sI = 0; sI < SPLIT; ++sI)
    v += (float)ep[idx + (long)sI * 524288];
  v *= A_UNSCALE;
  __bf16 b = (__bf16)v;
  embb[idx] = b;
  float f = (float)b;
  float s = f * f;
#pragma unroll
  for (int off = 32; off >= 1; off >>= 1) s += __shfl_xor(s, off);
  if (c == 0) sq[row] = s;
}

// ------- gemm1: hpart[s] = A[:,ks] @ XW1t^T, emits A8 tiled [k/64][row][64] ----
__global__ __launch_bounds__(256, 4) void k_gemm1(const float* __restrict__ A,
    const __bf16* __restrict__ Bt, __bf16* __restrict__ Cpart,
    unsigned char* __restrict__ A8) {
  constexpr int BM = 64, BK = 64, BN = 128;
  constexpr int KSUB = NN / SPLIT;          // 1024
  constexpr int KSTEPS = KSUB / BK;         // 16
  constexpr int LDA = BK + 8;               // 72: pad breaks power-of-2 conflicts
  constexpr int NT = 4, BCH = 4;

  __shared__ __bf16 Ab[BM * LDA];
  __shared__ __bf16 Bb[BN * LDA];

  const int t = threadIdx.x;
  const int mblk = blockIdx.x & 127;
  const int s = blockIdx.x >> 7;
  const long m0 = (long)mblk * BM;
  const long kbeg = (long)s * KSUB;

  const int lane = t & 63, w = t >> 6;
  const int q = lane >> 4, r16 = lane & 15;
  const int wr = w >> 1, wc = w & 1;        // 2x2 wave grid
  const int wrow = wr * 32, wcol = wc * 64;

  const int ar = t >> 3;                    // 0..31
  const int ac = t & 7;
  const float* Abase = A + (m0 + ar) * (long)NN + ac * 8;

  f32x4 av0[2], av1[2];
  u32x4 bv[BCH];
  long pend_kb = kbeg;

  auto load_tile = [&](long kb) {
    pend_kb = kb;
#pragma unroll
    for (int i = 0; i < 2; ++i) {
      const float* p = Abase + (long)i * 32 * NN + kb;
      av0[i] = *(const f32x4*)p;
      av1[i] = *(const f32x4*)(p + 4);
    }
#pragma unroll
    for (int i = 0; i < BCH; ++i) {
      int c = t + i * 256, n = c >> 3, cc = c & 7;
      bv[i] = *(const u32x4*)(Bt + (long)n * NN + kb + cc * 8);
    }
  };

  auto store_tile = [&]() {
    const long panel = (pend_kb >> 6) * ((long)NN * 64);
#pragma unroll
    for (int i = 0; i < 2; ++i) {
      // fp8 side-product, K-panel-tiled: contiguous 512 B per wave
      int lo = __builtin_amdgcn_cvt_pk_fp8_f32(av0[i][0] * A_SCALE, av0[i][1] * A_SCALE, 0, false);
      lo     = __builtin_amdgcn_cvt_pk_fp8_f32(av0[i][2] * A_SCALE, av0[i][3] * A_SCALE, lo, true);
      int hi = __builtin_amdgcn_cvt_pk_fp8_f32(av1[i][0] * A_SCALE, av1[i][1] * A_SCALE, 0, false);
      hi     = __builtin_amdgcn_cvt_pk_fp8_f32(av1[i][2] * A_SCALE, av1[i][3] * A_SCALE, hi, true);
      u32x2 p8; p8[0] = (uint32_t)lo; p8[1] = (uint32_t)hi;
      *(u32x2*)&A8[panel + (m0 + ar + i * 32) * 64 + ac * 8] = p8;
      // bf16 LDS tile for MFMA
      bf16x8 cv;
#pragma unroll
      for (int u = 0; u < 4; ++u) { cv[u] = (__bf16)av0[i][u]; cv[u + 4] = (__bf16)av1[i][u]; }
      *(bf16x8*)&Ab[(ar + i * 32) * LDA + ac * 8] = cv;
    }
#pragma unroll
    for (int i = 0; i < BCH; ++i) {
      int c = t + i * 256, n = c >> 3, cc = c & 7;
      *(u32x4*)&Bb[n * LDA + cc * 8] = bv[i];
    }
  };

  f32x4 zero = {0.f, 0.f, 0.f, 0.f};
  f32x4 acc[2][NT];
#pragma unroll
  for (int mt = 0; mt < 2; ++mt)
#pragma unroll
    for (int nt = 0; nt < NT; ++nt) acc[mt][nt] = zero;

  load_tile(kbeg);
  for (int kt = 0; kt < KSTEPS; ++kt) {
    __syncthreads();
    store_tile();
    __syncthreads();
    if (kt + 1 < KSTEPS) load_tile(kbeg + (long)(kt + 1) * BK);  // prefetch
#pragma unroll
    for (int ks = 0; ks < 2; ++ks) {
      bf16x8 af[2], bf[NT];
#pragma unroll
      for (int mt = 0; mt < 2; ++mt)
        af[mt] = *(const bf16x8*)&Ab[(wrow + mt * 16 + r16) * LDA + ks * 32 + q * 8];
#pragma unroll
      for (int nt = 0; nt < NT; ++nt)
        bf[nt] = *(const bf16x8*)&Bb[(wcol + nt * 16 + r16) * LDA + ks * 32 + q * 8];
#pragma unroll
      for (int mt = 0; mt < 2; ++mt)
#pragma unroll
        for (int nt = 0; nt < NT; ++nt)
          acc[mt][nt] = __builtin_amdgcn_mfma_f32_16x16x32_bf16(af[mt], bf[nt], acc[mt][nt], 0, 0, 0);
    }
  }

  __bf16* Cp = Cpart + ((long)s * NN + m0) * BN;
#pragma unroll
  for (int mt = 0; mt < 2; ++mt)
#pragma unroll
    for (int nt = 0; nt < NT; ++nt)
#pragma unroll
      for (int r = 0; r < 4; ++r) {
        int gm = wrow + mt * 16 + q * 4 + r;     // C row = (lane>>4)*4 + reg
        int gn = wcol + nt * 16 + r16;           // C col = lane&15
        Cp[(long)gm * BN + gn] = (__bf16)acc[mt][nt][r];
      }
}

// ------- gemm2: epart[s] = A8tiled @ Yt^T  (fp8 A -> bf16 MFMA) -------
__global__ __launch_bounds__(256, 4) void k_gemm2(const unsigned char* __restrict__ A8,
    const __bf16* __restrict__ Bt, __bf16* __restrict__ Cpart) {
  constexpr int BM = 64, BK = 64, BN = 64;
  constexpr int KSUB = NN / SPLIT;          // 1024
  constexpr int KSTEPS = KSUB / BK;         // 16
  constexpr int LDA = BK + 8;
  constexpr int NT = 2, BCH = 2;

  __shared__ __bf16 Ab[BM * LDA];
  __shared__ __bf16 Bb[BN * LDA];

  const int t = threadIdx.x;
  const int mblk = blockIdx.x & 127;
  const int s = blockIdx.x >> 7;
  const long m0 = (long)mblk * BM;
  const long kbeg = (long)s * KSUB;

  const int lane = t & 63, w = t >> 6;
  const int q = lane >> 4, r16 = lane & 15;
  const int wr = w >> 1, wc = w & 1;
  const int wrow = wr * 32, wcol = wc * 32;

  const int ar = t >> 2;                    // 0..63 (row within tile)
  const int ac4 = t & 3;                    // 16-byte chunk within 64-byte row

  u32x4 a8v;
  u32x4 bv[BCH];

  auto load_tile = [&](long kb) {
    // K-panel-tiled read: 1 KB contiguous per wave
    a8v = *(const u32x4*)(A8 + (kb >> 6) * ((long)NN * 64) + (m0 + ar) * 64 + ac4 * 16);
#pragma unroll
    for (int i = 0; i < BCH; ++i) {
      int c = t + i * 256, n = c >> 3, cc = c & 7;
      bv[i] = *(const u32x4*)(Bt + (long)n * NN + kb + cc * 8);
    }
  };

  auto store_tile = [&]() {
    bf16x8 c0, c1;
#pragma unroll
    for (int d = 0; d < 2; ++d) {
      f32x2 f01 = __builtin_amdgcn_cvt_pk_f32_fp8((int)a8v[d], false);
      f32x2 f23 = __builtin_amdgcn_cvt_pk_f32_fp8((int)a8v[d], true);
      c0[d * 4 + 0] = (__bf16)f01[0]; c0[d * 4 + 1] = (__bf16)f01[1];
      c0[d * 4 + 2] = (__bf16)f23[0]; c0[d * 4 + 3] = (__bf16)f23[1];
    }
#pragma unroll
    for (int d = 2; d < 4; ++d) {
      f32x2 f01 = __builtin_amdgcn_cvt_pk_f32_fp8((int)a8v[d], false);
      f32x2 f23 = __builtin_amdgcn_cvt_pk_f32_fp8((int)a8v[d], true);
      c1[(d - 2) * 4 + 0] = (__bf16)f01[0]; c1[(d - 2) * 4 + 1] = (__bf16)f01[1];
      c1[(d - 2) * 4 + 2] = (__bf16)f23[0]; c1[(d - 2) * 4 + 3] = (__bf16)f23[1];
    }
    *(bf16x8*)&Ab[ar * LDA + ac4 * 16] = c0;
    *(bf16x8*)&Ab[ar * LDA + ac4 * 16 + 8] = c1;
#pragma unroll
    for (int i = 0; i < BCH; ++i) {
      int c = t + i * 256, n = c >> 3, cc = c & 7;
      *(u32x4*)&Bb[n * LDA + cc * 8] = bv[i];
    }
  };

  f32x4 zero = {0.f, 0.f, 0.f, 0.f};
  f32x4 acc[2][NT];
#pragma unroll
  for (int mt = 0; mt < 2; ++mt)
#pragma unroll
    for (int nt = 0; nt < NT; ++nt) acc[mt][nt] = zero;

  load_tile(kbeg);
  for (int kt = 0; kt < KSTEPS; ++kt) {
    __syncthreads();
    store_tile();
    __syncthreads();
    if (kt + 1 < KSTEPS) load_tile(kbeg + (long)(kt + 1) * BK);
#pragma unroll
    for (int ks = 0; ks < 2; ++ks) {
      bf16x8 af[2], bf[NT];
#pragma unroll
      for (int mt = 0; mt < 2; ++mt)
        af[mt] = *(const bf16x8*)&Ab[(wrow + mt * 16 + r16) * LDA + ks * 32 + q * 8];
#pragma unroll
      for (int nt = 0; nt < NT; ++nt)
        bf[nt] = *(const bf16x8*)&Bb[(wcol + nt * 16 + r16) * LDA + ks * 32 + q * 8];
#pragma unroll
      for (int mt = 0; mt < 2; ++mt)
#pragma unroll
        for (int nt = 0; nt < NT; ++nt)
          acc[mt][nt] = __builtin_amdgcn_mfma_f32_16x16x32_bf16(af[mt], bf[nt], acc[mt][nt], 0, 0, 0);
    }
  }

  __bf16* Cp = Cpart + ((long)s * NN + m0) * BN;
#pragma unroll
  for (int mt = 0; mt < 2; ++mt)
#pragma unroll
    for (int nt = 0; nt < NT; ++nt)
#pragma unroll
      for (int r = 0; r < 4; ++r) {
        int gm = wrow + mt * 16 + q * 4 + r;
        int gn = wcol + nt * 16 + r16;
        Cp[(long)gm * BN + gn] = (__bf16)acc[mt][nt][r];
      }
}

// ------- pass1: row sums of exp(-relu(dist)) over triangular block pairs -------
__global__ __launch_bounds__(256, 2) void k_pass1(const __bf16* __restrict__ emb,
    const float* __restrict__ sq, float* __restrict__ rsum) {
  constexpr int LDE = 72;
  __shared__ __bf16 Ej[128 * LDE];   // A-operand: rows of j-block
  __shared__ __bf16 Ei[128 * LDE];   // B-operand: rows of i-block (C cols)
  __shared__ float sqi[128], sqj[128], rloci[128], rlocj[128];
  const int t = threadIdx.x;
  const int p = blockIdx.x;
  int bj = (int)((sqrtf(8.f * (float)p + 1.f) - 1.f) * 0.5f);
  while ((bj + 1) * (bj + 2) / 2 <= p) ++bj;
  while (bj * (bj + 1) / 2 > p) --bj;
  const int bi = p - bj * (bj + 1) / 2;
  const bool diag = (bi == bj);
  const long i0 = (long)bi * 128, j0 = (long)bj * 128;
#pragma unroll
  for (int i = 0; i < 4; ++i) {
    int c = t + i * 256, row = c >> 3, cc = c & 7;
    *(u32x4*)&Ej[row * LDE + cc * 8] = *(const u32x4*)(emb + (j0 + row) * EMB + cc * 8);
    *(u32x4*)&Ei[row * LDE + cc * 8] = *(const u32x4*)(emb + (i0 + row) * EMB + cc * 8);
  }
  if (t < 128) { sqi[t] = sq[i0 + t]; rloci[t] = 0.f; }
  else { sqj[t - 128] = sq[j0 + t - 128]; rlocj[t - 128] = 0.f; }
  __syncthreads();

  const int lane = t & 63, w = t >> 6, q = lane >> 4, r16 = lane & 15;
  const int jr = w >> 1, ic = w & 1;   // wave tile: 64 j-rows x 64 i-cols
  f32x4 zero = {0.f, 0.f, 0.f, 0.f};
  f32x4 acc[4][4];
#pragma unroll
  for (int a = 0; a < 4; ++a)
#pragma unroll
    for (int b = 0; b < 4; ++b) acc[a][b] = zero;
#pragma unroll
  for (int ks = 0; ks < 2; ++ks) {
    bf16x8 af[4], bf[4];
#pragma unroll
    for (int jt = 0; jt < 4; ++jt)
      af[jt] = *(const bf16x8*)&Ej[(jr * 64 + jt * 16 + r16) * LDE + ks * 32 + q * 8];
#pragma unroll
    for (int it = 0; it < 4; ++it)
      bf[it] = *(const bf16x8*)&Ei[(ic * 64 + it * 16 + r16) * LDE + ks * 32 + q * 8];
#pragma unroll
    for (int jt = 0; jt < 4; ++jt)
#pragma unroll
      for (int it = 0; it < 4; ++it)
        acc[jt][it] = __builtin_amdgcn_mfma_f32_16x16x32_bf16(af[jt], bf[it], acc[jt][it], 0, 0, 0);
  }

  float colp[4] = {0.f, 0.f, 0.f, 0.f};
  float rowp[4][4];
#pragma unroll
  for (int jt = 0; jt < 4; ++jt)
#pragma unroll
    for (int r = 0; r < 4; ++r) rowp[jt][r] = 0.f;
#pragma unroll
  for (int it = 0; it < 4; ++it) {
    const int il = ic * 64 + it * 16 + r16;
    const float si = sqi[il];
#pragma unroll
    for (int jt = 0; jt < 4; ++jt)
#pragma unroll
      for (int r = 0; r < 4; ++r) {
        const int jl = jr * 64 + jt * 16 + q * 4 + r;
        float d = fmaxf(si + sqj[jl] - 2.f * acc[jt][it][r], 0.f);
        float e = __expf(-d);
        colp[it] += e;
        rowp[jt][r] += e;
      }
  }
#pragma unroll
  for (int it = 0; it < 4; ++it) {
    float pp = colp[it];
    pp += __shfl_xor(pp, 16);
    pp += __shfl_xor(pp, 32);
    if (q == 0) atomicAdd(&rloci[ic * 64 + it * 16 + r16], pp);
  }
  if (!diag) {
#pragma unroll
    for (int jt = 0; jt < 4; ++jt)
#pragma unroll
      for (int r = 0; r < 4; ++r) {
        float pp = rowp[jt][r];
        pp += __shfl_xor(pp, 1);
        pp += __shfl_xor(pp, 2);
        pp += __shfl_xor(pp, 4);
        pp += __shfl_xor(pp, 8);
        if (r16 == 0) atomicAdd(&rlocj[jr * 64 + jt * 16 + q * 4 + r], pp);
      }
  }
  __syncthreads();
  if (t < 128) {
    atomicAdd(&rsum[i0 + t], rloci[t]);
    if (!diag) atomicAdd(&rsum[j0 + t], rlocj[t]);
  }
}

// ---------------- pass2: write out = exp(-relu(dist)) / rsum + EPS ----------------
__global__ __launch_bounds__(256, 2) void k_pass2(const __bf16* __restrict__ emb,
    const float* __restrict__ sq, const float* __restrict__ rsum,
    float* __restrict__ out) {
  constexpr int LDE = 72;
  __shared__ __bf16 Em[128 * LDE];
  __shared__ __bf16 En[128 * LDE];
  __shared__ float sqm[128], sqn[128], inv[128];
  const int t = threadIdx.x;
  const int bn = blockIdx.x & 63, bm = blockIdx.x >> 6;
  const long m0 = (long)bm * 128, n0 = (long)bn * 128;
#pragma unroll
  for (int i = 0; i < 4; ++i) {
    int c = t + i * 256, row = c >> 3, cc = c & 7;
    *(u32x4*)&Em[row * LDE + cc * 8] = *(const u32x4*)(emb + (m0 + row) * EMB + cc * 8);
    *(u32x4*)&En[row * LDE + cc * 8] = *(const u32x4*)(emb + (n0 + row) * EMB + cc * 8);
  }
  if (t < 128) { sqm[t] = sq[m0 + t]; inv[t] = 1.0f / rsum[m0 + t]; }
  else sqn[t - 128] = sq[n0 + t - 128];
  __syncthreads();

  const int lane = t & 63, w = t >> 6, q = lane >> 4, r16 = lane & 15;
  const int wr = w >> 1, wc = w & 1;
  f32x4 zero = {0.f, 0.f, 0.f, 0.f};
  f32x4 acc[4][4];
#pragma unroll
  for (int a = 0; a < 4; ++a)
#pragma unroll
    for (int b = 0; b < 4; ++b) acc[a][b] = zero;
#pragma unroll
  for (int ks = 0; ks < 2; ++ks) {
    bf16x8 af[4], bf[4];
#pragma unroll
    for (int mt = 0; mt < 4; ++mt)
      af[mt] = *(const bf16x8*)&Em[(wr * 64 + mt * 16 + r16) * LDE + ks * 32 + q * 8];
#pragma unroll
    for (int nt = 0; nt < 4; ++nt)
      bf[nt] = *(const bf16x8*)&En[(wc * 64 + nt * 16 + r16) * LDE + ks * 32 + q * 8];
#pragma unroll
    for (int mt = 0; mt < 4; ++mt)
#pragma unroll
      for (int nt = 0; nt < 4; ++nt)
        acc[mt][nt] = __builtin_amdgcn_mfma_f32_16x16x32_bf16(af[mt], bf[nt], acc[mt][nt], 0, 0, 0);
  }
#pragma unroll
  for (int mt = 0; mt < 4; ++mt)
#pragma unroll
    for (int nt = 0; nt < 4; ++nt) {
      const int jl = wc * 64 + nt * 16 + r16;
      const float sj = sqn[jl];
#pragma unroll
      for (int r = 0; r < 4; ++r) {
        const int il = wr * 64 + mt * 16 + q * 4 + r;
        float d = fmaxf(sqm[il] + sj - 2.f * acc[mt][nt][r], 0.f);
        float e = __expf(-d);
        out[(m0 + il) * (long)NN + n0 + jl] = fmaf(e, inv[il], 1e-10f);
      }
    }
}

extern "C" void kernel_launch(void* const* d_in, const int* in_sizes, int n_in,
                              void* d_out, int out_size, void* d_ws, size_t ws_size,
                              hipStream_t stream) {
  (void)in_sizes; (void)n_in; (void)out_size; (void)ws_size;
  const float* A  = (const float*)d_in[0];
  const float* X  = (const float*)d_in[1];
  const float* W1 = (const float*)d_in[2];
  const float* W2 = (const float*)d_in[3];
  float* out = (float*)d_out;

  char* w = (char*)d_ws;
  __bf16* hpartb = (__bf16*)w;                        // 16 MB [8][8192][128] bf16
  __bf16* epartb = (__bf16*)w;                        // reuse: 8 MB [8][8192][64]
  unsigned char* A8 = (unsigned char*)(w + (16u << 20));  // 64 MB fp8 tiled [128][8192][64]
  __bf16* xw1t  = (__bf16*)(w + (80u << 20));         // 2 MB  [128][8192]
  __bf16* ytp   = (__bf16*)(w + (82u << 20));         // 1 MB  [64][8192]
  __bf16* embb  = (__bf16*)(w + (83u << 20));         // 1 MB  [8192][64]
  float*  sq    = (float*)(w + (84u << 20));          // 32 KB
  float*  rsum  = (float*)(w + (84u << 20) + 32768);  // 32 KB

  k_xw1<<<4096, 256, 0, stream>>>(X, W1, xw1t, rsum);
  k_gemm1<<<1024, 256, 0, stream>>>(A, xw1t, hpartb, A8);
  k_rely<<<2048, 256, 0, stream>>>(hpartb, W2, ytp);
  k_gemm2<<<1024, 256, 0, stream>>>(A8, ytp, epartb);
  k_reduce2<<<2048, 256, 0, stream>>>(epartb, embb, sq);
  k_pass1<<<2080, 256, 0, stream>>>(embb, sq, rsum);
  k_pass2<<<4096, 256, 0, stream>>>(embb, sq, rsum, out);
}